// Round 3
// baseline (109214.001 us; speedup 1.0000x reference)
//
#include <hip/hip_runtime.h>
#include <hip/hip_bf16.h>

typedef __attribute__((ext_vector_type(8))) short bf16x8;
typedef __attribute__((ext_vector_type(4))) float f32x4;

// Problem sizes (fixed): B=64, L=1024, I=256, H=512
// d_in order: 0 inputs, 1 hidden_states, 2 w_ir, 3 w_iz, 4 w_in, 5 b_ir, 6 b_iz,
//             7 b_in, 8 w_hr, 9 w_hz, 10 w_hn, 11 b_hr, 12 b_hz, 13 b_hn

__device__ __forceinline__ unsigned short f2bf(float f) {
    __hip_bfloat16 h = __float2bfloat16(f);   // RNE
    return __builtin_bit_cast(unsigned short, h);
}
__device__ __forceinline__ float bf2f(unsigned short u) {
    union { unsigned int i; float f; } c; c.i = ((unsigned int)u) << 16; return c.f;
}

// Device-coherent store (bypass L1+L2, lands at the Infinity-Cache coherence
// point). Each dword is atomic end-to-end: tag and payload arrive together,
// so NO drain / flag / fence is needed anywhere in the exchange protocol.
__device__ __forceinline__ void store_tag(unsigned int* p, unsigned int v) {
    asm volatile("global_store_dword %0, %1, off sc0 sc1" :: "v"(p), "v"(v) : "memory");
}

// ---------------------------------------------------------------- pack inputs
// fp32 [64][1024][256] -> bf16 (rows m = b*1024+t are contiguous I=256)
__global__ void pack_inputs(const float* __restrict__ in, unsigned short* __restrict__ out) {
    int i = blockIdx.x * 256 + threadIdx.x;          // 16384 blocks: i < 4194304
    float4 v = reinterpret_cast<const float4*>(in)[i];
    ushort4 u;
    u.x = f2bf(v.x); u.y = f2bf(v.y); u.z = f2bf(v.z); u.w = f2bf(v.w);
    reinterpret_cast<ushort4*>(out)[i] = u;
}

// ---------------------------------------------------------------- pack weights
// Wx  bf16 [1536][256]  (n = g*512 + j; g: 0=r,1=z,2=n)
// Wh  bf16 [3][512][512]
// biasx fp32 [1536]: r: b_ir+b_hr, z: b_iz+b_hz, n: b_in (b_hn inside r*(...))
// Also zero-inits the tagged h-exchange buffer (tag 0 != any live tag >= 1);
// kernel-end L2 writeback makes the zeros visible to gru_scan's IC-scope polls.
__global__ void pack_weights(const float* __restrict__ w_ir, const float* __restrict__ w_iz,
                             const float* __restrict__ w_in, const float* __restrict__ b_ir,
                             const float* __restrict__ b_iz, const float* __restrict__ b_in,
                             const float* __restrict__ w_hr, const float* __restrict__ w_hz,
                             const float* __restrict__ w_hn, const float* __restrict__ b_hr,
                             const float* __restrict__ b_hz,
                             unsigned short* __restrict__ Wx, unsigned short* __restrict__ Wh,
                             float* __restrict__ biasx, unsigned int* __restrict__ Hbuf32) {
    int i = blockIdx.x * 256 + threadIdx.x;          // 3072 blocks: i < 786432
    {
        int g = i / 262144, rem = i % 262144;
        const float* src = (g == 0) ? w_hr : ((g == 1) ? w_hz : w_hn);
        Wh[i] = f2bf(src[rem]);
    }
    if (i < 393216) {
        int g = i / 131072, rem = i % 131072;
        const float* src = (g == 0) ? w_ir : ((g == 1) ? w_iz : w_in);
        Wx[i] = f2bf(src[rem]);
    }
    if (i < 1536) {
        int g = i / 512, j = i % 512;
        float v = (g == 0) ? (b_ir[j] + b_hr[j]) : ((g == 1) ? (b_iz[j] + b_hz[j]) : b_in[j]);
        biasx[i] = v;
    }
    if (i < 65536) Hbuf32[i] = 0u;   // both slots: 2*64*512 dwords
}

// ---------------------------------------------------------------- input projection GEMM
// C[m][n] = sum_k A[m][k]*Wx[n][k] + biasx[n],  M=65536, N=1536, K=256
// written as bf16 X[t][b][n] with t = m & 1023, b = m >> 10.
__global__ __launch_bounds__(256) void xproj_gemm(
    const unsigned short* __restrict__ A,    // [65536][256] bf16
    const unsigned short* __restrict__ Bw,   // [1536][256]  bf16
    const float* __restrict__ biasx,         // [1536]
    unsigned short* __restrict__ X)          // [1024][64][1536] bf16
{
    __shared__ __attribute__((aligned(16))) unsigned short Al[64][40]; // +8 pad
    __shared__ __attribute__((aligned(16))) unsigned short Bl[64][40];
    const int tid  = threadIdx.x;
    const int m0   = blockIdx.x * 64;
    const int n0   = blockIdx.y * 64;
    const int lane = tid & 63;
    const int wv   = tid >> 6;
    const int quad = lane >> 4;
    const int l16  = lane & 15;
    const int mw   = (wv & 1) * 32;
    const int nw   = (wv >> 1) * 32;
    const int lr   = tid >> 2;          // 0..63 staging row
    const int lc   = (tid & 3) * 8;     // k offset within BK=32

    f32x4 acc[2][2] = {};

    for (int kb = 0; kb < 8; ++kb) {
        uint4 av = *reinterpret_cast<const uint4*>(A  + (size_t)(m0 + lr) * 256 + kb * 32 + lc);
        uint4 bv = *reinterpret_cast<const uint4*>(Bw + (size_t)(n0 + lr) * 256 + kb * 32 + lc);
        __syncthreads();
        *reinterpret_cast<uint4*>(&Al[lr][lc]) = av;
        *reinterpret_cast<uint4*>(&Bl[lr][lc]) = bv;
        __syncthreads();
        bf16x8 af[2], bfg[2];
#pragma unroll
        for (int s = 0; s < 2; ++s) {
            af[s]  = *reinterpret_cast<const bf16x8*>(&Al[mw + s * 16 + l16][quad * 8]);
            bfg[s] = *reinterpret_cast<const bf16x8*>(&Bl[nw + s * 16 + l16][quad * 8]);
        }
#pragma unroll
        for (int sm = 0; sm < 2; ++sm)
#pragma unroll
            for (int sn = 0; sn < 2; ++sn)
                acc[sm][sn] = __builtin_amdgcn_mfma_f32_16x16x32_bf16(af[sm], bfg[sn], acc[sm][sn], 0, 0, 0);
    }
    // epilogue: D layout col = lane&15 (n), row = quad*4 + r (m)
#pragma unroll
    for (int sn = 0; sn < 2; ++sn) {
        int n = n0 + nw + sn * 16 + l16;
        float bias = biasx[n];
#pragma unroll
        for (int sm = 0; sm < 2; ++sm)
#pragma unroll
            for (int r = 0; r < 4; ++r) {
                int m = m0 + mw + sm * 16 + quad * 4 + r;
                int t = m & 1023, b = m >> 10;
                X[(size_t)(t * 64 + b) * 1536 + n] = f2bf(acc[sm][sn][r] + bias);
            }
    }
}

// ---------------------------------------------------------------- recurrent scan
// 8 workgroups x 512 threads (8 waves). Block bid owns dims [bid*64, bid*64+64)
// per gate. Wave wv = ns + 4*kh: dim sub-tile ns (16 dims), k-half kh. Every
// wave computes M=64 (all batch rows) x N=48 (3 gates x 16 dims) x K=256.
// Weight B-fragments: 96 VGPR/lane, register-resident for all 1024 steps.
//
// WHY 8 BLOCKS: the cross-block h all-to-all is (#blocks) x 128KB/step of
// device-coherent traffic; round-2's 32 blocks = 4MB/retry-round saturated
// the coherence point (dur 2x WORSE despite 1-RT protocol). 8 blocks cut
// poll traffic and poller count 4x; the A-operand (all 64 rows) is staged
// ONCE per block into a swizzled LDS slab and read 4x-redundantly from LDS
// (free) instead of from the IC (expensive).
//
// STAGING: 8 waves each own a (16-row x 256-k) slice: lane (quad,jl) polls
// 4 rows x 8 contiguous u64 (one 64B line each) of tagged dwords
//   Hbuf32[slot][b][j] = (tag<<16) | bf16(h), slot=t&1, tag=(t>>1)+1,
// strips tags, writes the slab; retries re-read only this slice. Overwrite
// safety (grid-wide induction): a producer publishes h_{t+3} only after
// staging ALL of h_{t+2}, which certifies every block passed its step-t+1
// barrier B, which certifies every wave finished reading h_{t+1}.
// LDS slab is XOR-swizzled (byte ^= (row&7)<<4): staged writes and b128
// fragment reads both spread across all 8 16B-columns (conflict-free).
__global__ __launch_bounds__(512, 1) void gru_scan(
    const unsigned short* __restrict__ X,    // [1024][64][1536] bf16 (biases folded)
    const unsigned short* __restrict__ Wh,   // [3][512][512] bf16
    const float* __restrict__ h0,            // [1][64][512]
    const float* __restrict__ b_hn,          // [512]
    unsigned int* __restrict__ Hbuf32,       // [2][64][512] tagged dwords (pre-zeroed)
    float* __restrict__ out)                 // [64][1024][512] fp32, then hlast [64][512]
{
    const int tid  = threadIdx.x;
    const int lane = tid & 63;
    const int wv   = tid >> 6;      // wave 0..7
    const int ns   = wv & 3;        // dim sub-tile: dims [ns*16, ns*16+16) of block's 64
    const int kh   = wv >> 2;       // k-half: 0 -> [0,256), 1 -> [256,512)
    const int quad = lane >> 4;
    const int jl   = lane & 15;
    const int bid  = blockIdx.x;    // 0..7
    const int jg   = bid * 64 + ns * 16 + jl;  // this lane's output dim (per gate)

    // LDS: h slab (64 rows x 512 k bf16, swizzled) + kh-partial exchange
    __shared__ __attribute__((aligned(16))) unsigned char slab[65536];
    __shared__ __attribute__((aligned(16))) f32x4 red[4 * 12 * 64];   // 49152 B

    // Weight B-fragments for this (ns, kh): lane jl holds row j=jg,
    // k = kh*256 + kk*32 + quad*8 + (0..7) -> contiguous 16B from Wh[g][jg][...]
    bf16x8 bfrag[3][8];
#pragma unroll
    for (int g = 0; g < 3; ++g)
#pragma unroll
        for (int kk = 0; kk < 8; ++kk) {
            uint4 v = *reinterpret_cast<const uint4*>(
                Wh + (size_t)(g * 512 + jg) * 512 + kh * 256 + kk * 32 + quad * 8);
            bfrag[g][kk] = __builtin_bit_cast(bf16x8, v);
        }
    const float bhn = b_hn[jg];

    // init: kh0 waves publish tagged h0 (tag 1, slot 0) for all 64 rows of
    // their 16 dims, keep fp32 h_reg, and preload x projections for t=0.
    float h_reg[16];
    unsigned int xp[24];   // packed bf16 pairs: [(g*4+mt)*2 + (r>>1)]
    if (kh == 0) {
#pragma unroll
        for (int mt = 0; mt < 4; ++mt)
#pragma unroll
            for (int r = 0; r < 4; ++r) {
                int b = mt * 16 + quad * 4 + r;
                float h = h0[b * 512 + jg];
                h_reg[mt * 4 + r] = h;
                store_tag(&Hbuf32[(size_t)b * 512 + jg], (1u << 16) | (unsigned int)f2bf(h));
            }
#pragma unroll
        for (int g = 0; g < 3; ++g)
#pragma unroll
            for (int mt = 0; mt < 4; ++mt)
#pragma unroll
                for (int rp = 0; rp < 2; ++rp) {
                    int b0 = mt * 16 + quad * 4 + rp * 2;
                    unsigned int lo = X[(size_t)b0 * 1536 + g * 512 + jg];
                    unsigned int hi = X[(size_t)(b0 + 1) * 1536 + g * 512 + jg];
                    xp[(g * 4 + mt) * 2 + rp] = lo | (hi << 16);
                }
    }

    const unsigned long long* hb = reinterpret_cast<const unsigned long long*>(Hbuf32);
    const int kb2   = kh * 128 + jl * 8;    // u64 offset of staged 16-k chunk within a row
    const int kbyte = kh * 512 + jl * 32;   // byte offset of same chunk within a slab row
    const int swz   = (jl & 7) << 4;        // slab swizzle term for MFMA reads (row&7 == jl&7)

    for (int t = 0; t < 1024; ++t) {
        const int cur = t & 1;
        const unsigned int tag  = (unsigned int)((t >> 1) + 1);
        const unsigned int tag2 = tag | (tag << 16);
        const unsigned long long* hbs = hb + (size_t)cur * 16384;

        // ---- stage this wave's (16 rows x 256 k) slice: poll tagged dwords,
        // strip tags, write swizzled slab. Retry re-reads only this slice.
        for (;;) {
            unsigned long long w[32];
#pragma unroll
            for (int rr = 0; rr < 4; ++rr) {
                const int row = ns * 16 + quad * 4 + rr;
                const unsigned long long* p = hbs + row * 256 + kb2;
#pragma unroll
                for (int i = 0; i < 8; ++i)
                    w[rr * 8 + i] = __hip_atomic_load(p + i, __ATOMIC_RELAXED,
                                                      __HIP_MEMORY_SCOPE_AGENT);
            }
            unsigned int err = 0u;
#pragma unroll
            for (int rr = 0; rr < 4; ++rr) {
                const int row = ns * 16 + quad * 4 + rr;
                unsigned int u[8];
#pragma unroll
                for (int i = 0; i < 8; ++i) {
                    unsigned long long ww = w[rr * 8 + i];
                    unsigned int hi = ((unsigned int)(ww >> 16) & 0xFFFFu) |
                                      ((unsigned int)(ww >> 48) << 16);
                    err |= hi ^ tag2;
                    u[i] = ((unsigned int)ww & 0xFFFFu) | ((unsigned int)(ww >> 32) << 16);
                }
                uint4 v0; v0.x = u[0]; v0.y = u[1]; v0.z = u[2]; v0.w = u[3];
                uint4 v1; v1.x = u[4]; v1.y = u[5]; v1.z = u[6]; v1.w = u[7];
                const unsigned int base = (unsigned int)(row << 10);
                *reinterpret_cast<uint4*>(slab + ((base + kbyte)      ^ ((row & 7) << 4))) = v0;
                *reinterpret_cast<uint4*>(slab + ((base + kbyte + 16) ^ ((row & 7) << 4))) = v1;
            }
            if (__all(err == 0u)) break;
        }
        __syncthreads();   // barrier A: slab complete

        // ---- MFMA: M=64 x N=48 x K=256 from LDS slab + register B-fragments
        f32x4 acc[4][3];
#pragma unroll
        for (int mt = 0; mt < 4; ++mt)
#pragma unroll
            for (int g = 0; g < 3; ++g) {
                f32x4 z = {0.f, 0.f, 0.f, 0.f};
                acc[mt][g] = z;
            }
#pragma unroll
        for (int kk = 0; kk < 8; ++kk)
#pragma unroll
            for (int mt = 0; mt < 4; ++mt) {
                const int row = mt * 16 + jl;
                bf16x8 af = *reinterpret_cast<const bf16x8*>(
                    slab + (((unsigned int)(row << 10) + (unsigned int)(kh * 512 + kk * 64 + quad * 16)) ^ swz));
#pragma unroll
                for (int g = 0; g < 3; ++g)
                    acc[mt][g] = __builtin_amdgcn_mfma_f32_16x16x32_bf16(af, bfrag[g][kk], acc[mt][g], 0, 0, 0);
            }

        if (kh == 1) {
#pragma unroll
            for (int mt = 0; mt < 4; ++mt)
#pragma unroll
                for (int g = 0; g < 3; ++g)
                    red[(ns * 12 + mt * 3 + g) * 64 + lane] = acc[mt][g];
        }
        __syncthreads();   // barrier B: partials visible

        if (kh == 0) {
#pragma unroll
            for (int mt = 0; mt < 4; ++mt)
#pragma unroll
                for (int g = 0; g < 3; ++g)
                    acc[mt][g] += red[(ns * 12 + mt * 3 + g) * 64 + lane];

            const int nslot = (t + 1) & 1;
            const unsigned int ntag = (unsigned int)(((t + 1) >> 1) + 1) << 16;
            unsigned int* Hn = Hbuf32 + (size_t)nslot * 32768;
#pragma unroll
            for (int mt = 0; mt < 4; ++mt)
#pragma unroll
                for (int r = 0; r < 4; ++r) {
                    const int b  = mt * 16 + quad * 4 + r;
                    const int hi = mt * 4 + r;
                    const int sh = (r & 1) * 16;
                    float xr = bf2f((unsigned short)(xp[(0 * 4 + mt) * 2 + (r >> 1)] >> sh));
                    float xz = bf2f((unsigned short)(xp[(1 * 4 + mt) * 2 + (r >> 1)] >> sh));
                    float xn = bf2f((unsigned short)(xp[(2 * 4 + mt) * 2 + (r >> 1)] >> sh));
                    float rv = 1.f / (1.f + __expf(-(xr + acc[0 + mt * 0][0][r])));
                    // (note: acc index is [mt][g]; spelled out below for clarity)
                    rv = 1.f / (1.f + __expf(-(xr + acc[mt][0][r])));
                    float zv = 1.f / (1.f + __expf(-(xz + acc[mt][1][r])));
                    float na = xn + rv * (acc[mt][2][r] + bhn);
                    float nv = 1.f - 2.f / (1.f + __expf(2.f * na));   // tanh, inf-safe
                    float h  = (1.f - zv) * nv + zv * h_reg[hi];
                    h_reg[hi] = h;
                    if (t < 1023)   // publish ASAP: this store IS the sync
                        store_tag(&Hn[b * 512 + jg], ntag | (unsigned int)f2bf(h));
                    out[(size_t)b * (1024 * 512) + (size_t)t * 512 + jg] = h;
                }
            if (t < 1023) {
                // prefetch next step's x projections; complete during next poll
                const unsigned short* Xt = X + (size_t)(t + 1) * (64 * 1536);
#pragma unroll
                for (int g = 0; g < 3; ++g)
#pragma unroll
                    for (int mt = 0; mt < 4; ++mt)
#pragma unroll
                        for (int rp = 0; rp < 2; ++rp) {
                            int b0 = mt * 16 + quad * 4 + rp * 2;
                            unsigned int lo = Xt[(size_t)b0 * 1536 + g * 512 + jg];
                            unsigned int hi2 = Xt[(size_t)(b0 + 1) * 1536 + g * 512 + jg];
                            xp[(g * 4 + mt) * 2 + rp] = lo | (hi2 << 16);
                        }
            } else {
#pragma unroll
                for (int mt = 0; mt < 4; ++mt)
#pragma unroll
                    for (int r = 0; r < 4; ++r) {
                        int b = mt * 16 + quad * 4 + r;
                        out[(size_t)(64 * 1024 * 512) + b * 512 + jg] = h_reg[mt * 4 + r];
                    }
            }
        }
    }
}

// ---------------------------------------------------------------- host
extern "C" void kernel_launch(void* const* d_in, const int* in_sizes, int n_in,
                              void* d_out, int out_size, void* d_ws, size_t ws_size,
                              hipStream_t stream) {
    const float* inputs = (const float*)d_in[0];
    const float* h0     = (const float*)d_in[1];
    const float* w_ir   = (const float*)d_in[2];
    const float* w_iz   = (const float*)d_in[3];
    const float* w_in   = (const float*)d_in[4];
    const float* b_ir   = (const float*)d_in[5];
    const float* b_iz   = (const float*)d_in[6];
    const float* b_in   = (const float*)d_in[7];
    const float* w_hr   = (const float*)d_in[8];
    const float* w_hz   = (const float*)d_in[9];
    const float* w_hn   = (const float*)d_in[10];
    const float* b_hr   = (const float*)d_in[11];
    const float* b_hz   = (const float*)d_in[12];
    const float* b_hn   = (const float*)d_in[13];
    float* out = (float*)d_out;

    // ws layout (16B aligned)
    char* wsb = (char*)d_ws;
    unsigned short* X      = (unsigned short*)(wsb);              // 201326592 B
    unsigned short* Abf    = (unsigned short*)(wsb + 201326592);  //  33554432 B
    unsigned short* Wx     = (unsigned short*)(wsb + 234881024);  //    786432 B
    unsigned short* Wh     = (unsigned short*)(wsb + 235667456);  //   1572864 B
    float*          biasx  = (float*)        (wsb + 237240320);   //      6144 B
    unsigned int*   Hbuf32 = (unsigned int*) (wsb + 237246464);   //    262144 B (end 237508608)

    pack_inputs<<<16384, 256, 0, stream>>>(inputs, Abf);
    pack_weights<<<3072, 256, 0, stream>>>(w_ir, w_iz, w_in, b_ir, b_iz, b_in,
                                           w_hr, w_hz, w_hn, b_hr, b_hz, Wx, Wh, biasx, Hbuf32);
    xproj_gemm<<<dim3(1024, 24), 256, 0, stream>>>(Abf, Wx, biasx, X);
    gru_scan<<<8, 512, 0, stream>>>(X, Wh, h0, b_hn, Hbuf32, out);
}

// Round 4
// 4633.394 us; speedup vs baseline: 23.5711x; 23.5711x over previous
//
#include <hip/hip_runtime.h>
#include <hip/hip_bf16.h>

typedef __attribute__((ext_vector_type(8))) short bf16x8;
typedef __attribute__((ext_vector_type(4))) float f32x4;

// Problem sizes (fixed): B=64, L=1024, I=256, H=512
// d_in order: 0 inputs, 1 hidden_states, 2 w_ir, 3 w_iz, 4 w_in, 5 b_ir, 6 b_iz,
//             7 b_in, 8 w_hr, 9 w_hz, 10 w_hn, 11 b_hr, 12 b_hz, 13 b_hn

__device__ __forceinline__ unsigned short f2bf(float f) {
    __hip_bfloat16 h = __float2bfloat16(f);   // RNE
    return __builtin_bit_cast(unsigned short, h);
}
__device__ __forceinline__ float bf2f(unsigned short u) {
    union { unsigned int i; float f; } c; c.i = ((unsigned int)u) << 16; return c.f;
}

// Device-coherent accesses (sc0 sc1 = land at / read from the Infinity-Cache
// coherence point, bypassing the non-coherent per-XCD L2).
__device__ __forceinline__ void store_h64(unsigned long long* p, unsigned long long v) {
    asm volatile("global_store_dwordx2 %0, %1, off sc0 sc1" :: "v"(p), "v"(v) : "memory");
}
__device__ __forceinline__ void store_flag(unsigned int* p, unsigned int v) {
    asm volatile("global_store_dword %0, %1, off sc0 sc1" :: "v"(p), "v"(v) : "memory");
}
__device__ __forceinline__ void vmem_drain() {
    asm volatile("s_waitcnt vmcnt(0)" ::: "memory");
}
__device__ __forceinline__ void lds_drain() {
    asm volatile("s_waitcnt lgkmcnt(0)" ::: "memory");
}

// ---------------------------------------------------------------- pack inputs
// fp32 [64][1024][256] -> bf16 (rows m = b*1024+t are contiguous I=256)
__global__ void pack_inputs(const float* __restrict__ in, unsigned short* __restrict__ out) {
    int i = blockIdx.x * 256 + threadIdx.x;          // 16384 blocks: i < 4194304
    float4 v = reinterpret_cast<const float4*>(in)[i];
    ushort4 u;
    u.x = f2bf(v.x); u.y = f2bf(v.y); u.z = f2bf(v.z); u.w = f2bf(v.w);
    reinterpret_cast<ushort4*>(out)[i] = u;
}

// ---------------------------------------------------------------- pack weights
// Wx  bf16 [1536][256]  (n = g*512 + j; g: 0=r,1=z,2=n)
// Wh  bf16 [3][512][512]
// biasx fp32 [1536]: r: b_ir+b_hr, z: b_iz+b_hz, n: b_in (b_hn inside r*(...))
// Also zero-inits the 128 per-wave-tile flags (one 128B line each; ws is
// re-poisoned every call; kernel-end L2 writeback publishes the zeros).
__global__ void pack_weights(const float* __restrict__ w_ir, const float* __restrict__ w_iz,
                             const float* __restrict__ w_in, const float* __restrict__ b_ir,
                             const float* __restrict__ b_iz, const float* __restrict__ b_in,
                             const float* __restrict__ w_hr, const float* __restrict__ w_hz,
                             const float* __restrict__ w_hn, const float* __restrict__ b_hr,
                             const float* __restrict__ b_hz,
                             unsigned short* __restrict__ Wx, unsigned short* __restrict__ Wh,
                             float* __restrict__ biasx, unsigned int* __restrict__ flags) {
    int i = blockIdx.x * 256 + threadIdx.x;          // 3072 blocks: i < 786432
    {
        int g = i / 262144, rem = i % 262144;
        const float* src = (g == 0) ? w_hr : ((g == 1) ? w_hz : w_hn);
        Wh[i] = f2bf(src[rem]);
    }
    if (i < 393216) {
        int g = i / 131072, rem = i % 131072;
        const float* src = (g == 0) ? w_ir : ((g == 1) ? w_iz : w_in);
        Wx[i] = f2bf(src[rem]);
    }
    if (i < 1536) {
        int g = i / 512, j = i % 512;
        float v = (g == 0) ? (b_ir[j] + b_hr[j]) : ((g == 1) ? (b_iz[j] + b_hz[j]) : b_in[j]);
        biasx[i] = v;
    }
    if (i < 4096) flags[i] = 0u;   // 128 flags x 32 dwords (128 B lines)
}

// ---------------------------------------------------------------- input projection GEMM
// C[m][n] = sum_k A[m][k]*Wx[n][k] + biasx[n],  M=65536, N=1536, K=256
// written as bf16 X[t][b][n] with t = m & 1023, b = m >> 10.
__global__ __launch_bounds__(256) void xproj_gemm(
    const unsigned short* __restrict__ A,    // [65536][256] bf16
    const unsigned short* __restrict__ Bw,   // [1536][256]  bf16
    const float* __restrict__ biasx,         // [1536]
    unsigned short* __restrict__ X)          // [1024][64][1536] bf16
{
    __shared__ __attribute__((aligned(16))) unsigned short Al[64][40]; // +8 pad
    __shared__ __attribute__((aligned(16))) unsigned short Bl[64][40];
    const int tid  = threadIdx.x;
    const int m0   = blockIdx.x * 64;
    const int n0   = blockIdx.y * 64;
    const int lane = tid & 63;
    const int wv   = tid >> 6;
    const int quad = lane >> 4;
    const int l16  = lane & 15;
    const int mw   = (wv & 1) * 32;
    const int nw   = (wv >> 1) * 32;
    const int lr   = tid >> 2;          // 0..63 staging row
    const int lc   = (tid & 3) * 8;     // k offset within BK=32

    f32x4 acc[2][2] = {};

    for (int kb = 0; kb < 8; ++kb) {
        uint4 av = *reinterpret_cast<const uint4*>(A  + (size_t)(m0 + lr) * 256 + kb * 32 + lc);
        uint4 bv = *reinterpret_cast<const uint4*>(Bw + (size_t)(n0 + lr) * 256 + kb * 32 + lc);
        __syncthreads();
        *reinterpret_cast<uint4*>(&Al[lr][lc]) = av;
        *reinterpret_cast<uint4*>(&Bl[lr][lc]) = bv;
        __syncthreads();
        bf16x8 af[2], bfg[2];
#pragma unroll
        for (int s = 0; s < 2; ++s) {
            af[s]  = *reinterpret_cast<const bf16x8*>(&Al[mw + s * 16 + l16][quad * 8]);
            bfg[s] = *reinterpret_cast<const bf16x8*>(&Bl[nw + s * 16 + l16][quad * 8]);
        }
#pragma unroll
        for (int sm = 0; sm < 2; ++sm)
#pragma unroll
            for (int sn = 0; sn < 2; ++sn)
                acc[sm][sn] = __builtin_amdgcn_mfma_f32_16x16x32_bf16(af[sm], bfg[sn], acc[sm][sn], 0, 0, 0);
    }
    // epilogue: D layout col = lane&15 (n), row = quad*4 + r (m)
#pragma unroll
    for (int sn = 0; sn < 2; ++sn) {
        int n = n0 + nw + sn * 16 + l16;
        float bias = biasx[n];
#pragma unroll
        for (int sm = 0; sm < 2; ++sm)
#pragma unroll
            for (int r = 0; r < 4; ++r) {
                int m = m0 + mw + sm * 16 + quad * 4 + r;
                int t = m & 1023, b = m >> 10;
                X[(size_t)(t * 64 + b) * 1536 + n] = f2bf(acc[sm][sn][r] + bias);
            }
    }
}

// ---------------------------------------------------------------- recurrent scan
// 32 workgroups x 512 threads (8 waves), 1 block/CU co-resident. Block bid
// owns output dims [bid*16, bid*16+16) per gate. Wave wv = mg + 4*kh: batch
// rows [mg*16, mg*16+16), k-half kh. Weight B-fragments: 96 VGPR/lane,
// register-resident for all 1024 steps.
//
// COALESCED TILE EXCHANGE: h lives in Hp as 512B tiles T[row16][col16] bf16,
// tile (ktile, mg) = rows [mg*16..+16) x dims [ktile*16..+16), two slots by
// t&1. Producer wave (kh0, block bid, plane mg) transposes its 16x16 h-tile
// through a 512B LDS scratch (intra-wave, lgkmcnt only) and publishes it with
// ONE global_store_dwordx2 per lane = one contiguous 512B wave-store. The
// release drain therefore waits on a single coalesced store. Consumers read
// A-fragments as 2 adjacent u64/lane per kk — each instruction covers 1KB
// contiguous. (Round-3 lesson: scattered fine-grained device-scope traffic
// congests the coherence fabric; everything here is line-coalesced.)
//
// PARTIAL-ORDER SYNC: 128 flags, one per (ktile, mg). Consumer wave (mg,kh)
// polls only its 16 producer flags (ktiles of its k-half, its mg plane).
// Safety of the 2-slot buffer: within a plane mg, every step's publish
// transitively requires all 32 ktile producers of that plane (kh1 partner's
// poll covers the other half via the shared red-barrier), so plane skew <= 1
// step; a flag value t+2 also certifies (via that block's barrier) that its
// kh1 wave finished reading step-t data. ONE __syncthreads per step.
__global__ __launch_bounds__(512, 1) void gru_scan(
    const unsigned short* __restrict__ X,    // [1024][64][1536] bf16 (biases folded)
    const unsigned short* __restrict__ Wh,   // [3][512][512] bf16
    const float* __restrict__ h0,            // [1][64][512]
    const float* __restrict__ b_hn,          // [512]
    unsigned long long* __restrict__ Hp64,   // [2][4 mg][32 ktile][64] u64 tiles
    unsigned int* __restrict__ flags,        // [128*32] (zeroed by pack_weights)
    float* __restrict__ out)                 // [64][1024][512] fp32, then hlast [64][512]
{
    const int tid  = threadIdx.x;
    const int lane = tid & 63;
    const int wv   = tid >> 6;      // wave 0..7
    const int mg   = wv & 3;        // batch-row plane: rows mg*16 .. mg*16+15
    const int kh   = wv >> 2;       // k-half: 0 -> [0,256), 1 -> [256,512)
    const int quad = lane >> 4;
    const int jl   = lane & 15;
    const int bid  = blockIdx.x;    // 0..31
    const int jg   = bid * 16 + jl; // this lane's output dim (per gate)

    __shared__ __attribute__((aligned(16))) f32x4 red[2][3][4][64];     // 24576 B
    __shared__ __attribute__((aligned(16))) unsigned short tsc[4][256]; // 2048 B transpose scratch

    // Weight B-fragments for this k-half: lane jl holds row j=jg,
    // k = kh*256 + kk*32 + quad*8 + (0..7) -> contiguous 16B from Wh[g][jg][...]
    bf16x8 bfrag[3][8];
#pragma unroll
    for (int g = 0; g < 3; ++g)
#pragma unroll
        for (int kk = 0; kk < 8; ++kk) {
            uint4 v = *reinterpret_cast<const uint4*>(
                Wh + (size_t)(g * 512 + jg) * 512 + kh * 256 + kk * 32 + quad * 8);
            bfrag[g][kk] = __builtin_bit_cast(bf16x8, v);
        }
    const float bhn = b_hn[jg];

    unsigned int* const flag_my = flags + (bid * 4 + mg) * 32;
    const unsigned int* const fpoll = flags + ((kh * 16 + jl) * 4 + mg) * 32;

    // u64 index of this lane's slot inside its produced tile (bijective 0..63):
    // tile layout T[row][col] bf16 -> lane writes rows lane&15, cols (lane>>4)*4..+3
    const int myslot = (lane & 15) * 4 + (lane >> 4);

    // init: kh0 waves publish transposed h0 tiles (slot 0) + flag = 1.
    float h_reg[4];
    float xv[3][4];
    if (kh == 0) {
#pragma unroll
        for (int r = 0; r < 4; ++r) {
            int b = mg * 16 + quad * 4 + r;
            float h = h0[b * 512 + jg];
            h_reg[r] = h;
            tsc[mg][(quad * 4 + r) * 16 + jl] = f2bf(h);   // T[row][col]
        }
        lds_drain();   // intra-wave cross-lane: lgkmcnt(0) suffices (lockstep)
        {
            unsigned long long tv = *reinterpret_cast<const unsigned long long*>(
                &tsc[mg][(lane & 15) * 16 + (lane >> 4) * 4]);
            store_h64(Hp64 + ((size_t)mg * 32 + bid) * 64 + myslot, tv);
        }
        vmem_drain();
        if (lane == 0) store_flag(flag_my, 1u);
        // preload x projections for t=0 (off the release path)
#pragma unroll
        for (int r = 0; r < 4; ++r) {
            int b = mg * 16 + quad * 4 + r;
#pragma unroll
            for (int g = 0; g < 3; ++g)
                xv[g][r] = bf2f(X[(size_t)b * 1536 + g * 512 + jg]);
        }
    }

    for (int t = 0; t < 1024; ++t) {
        const int cur = t & 1;
        const unsigned int tgt = (unsigned int)(t + 1);

        // ---- partial-order wait: only MY 16 producer tiles (k-half kh, plane mg)
        {
            unsigned int v;
            do { v = __hip_atomic_load(fpoll, __ATOMIC_RELAXED, __HIP_MEMORY_SCOPE_AGENT); }
            while (!__all((int)(v >= tgt)));
        }

        // ---- A-fragments from Hp tiles: per kk one 1KB-contiguous wave read.
        // lane (quad,jl) needs A[row=mg*16+jl][k = kh*256 + kk*32 + quad*8 ..+7]
        //  -> tile ktile = kh*16 + kk*2 + (quad>>1), bytes row*32 + (quad&1)*16.
        bf16x8 afrag[8];
        {
            const unsigned long long* bs = Hp64 + ((size_t)cur * 4 + mg) * 32 * 64;
#pragma unroll
            for (int kk = 0; kk < 8; ++kk) {
                const int idx = (kh * 16 + kk * 2 + (quad >> 1)) * 64 + jl * 4 + (quad & 1) * 2;
                unsigned long long lo = __hip_atomic_load(bs + idx,     __ATOMIC_RELAXED, __HIP_MEMORY_SCOPE_AGENT);
                unsigned long long hi = __hip_atomic_load(bs + idx + 1, __ATOMIC_RELAXED, __HIP_MEMORY_SCOPE_AGENT);
                ulonglong2 u; u.x = lo; u.y = hi;
                afrag[kk] = __builtin_bit_cast(bf16x8, u);
            }
        }

        f32x4 acc[3];
#pragma unroll
        for (int g = 0; g < 3; ++g) {
            f32x4 a = {0.f, 0.f, 0.f, 0.f};
#pragma unroll
            for (int kk = 0; kk < 8; ++kk)
                a = __builtin_amdgcn_mfma_f32_16x16x32_bf16(afrag[kk], bfrag[g][kk], a, 0, 0, 0);
            acc[g] = a;
        }

        if (kh == 1) {
#pragma unroll
            for (int g = 0; g < 3; ++g)
                red[cur][g][mg][lane] = acc[g];
        }
        __syncthreads();   // the ONLY barrier per step (red ping-pongs on t&1)

        if (kh == 0) {
#pragma unroll
            for (int g = 0; g < 3; ++g)
                acc[g] += red[cur][g][mg][lane];

#pragma unroll
            for (int r = 0; r < 4; ++r) {
                float rv = 1.f / (1.f + __expf(-(xv[0][r] + acc[0][r])));
                float zv = 1.f / (1.f + __expf(-(xv[1][r] + acc[1][r])));
                float na = xv[2][r] + rv * (acc[2][r] + bhn);
                float nv = 1.f - 2.f / (1.f + __expf(2.f * na));   // tanh, inf-safe
                float h  = (1.f - zv) * nv + zv * h_reg[r];
                h_reg[r] = h;
                tsc[mg][(quad * 4 + r) * 16 + jl] = f2bf(h);       // T[row][col]
            }
            if (t < 1023) {
                lds_drain();   // intra-wave transpose complete
                unsigned long long tv = *reinterpret_cast<const unsigned long long*>(
                    &tsc[mg][(lane & 15) * 16 + (lane >> 4) * 4]);
                store_h64(Hp64 + (((size_t)((t + 1) & 1) * 4 + mg) * 32 + bid) * 64 + myslot, tv);
                // release: ONE coalesced 512B wave-store to ack, then the flag
                vmem_drain();
                if (lane == 0) store_flag(flag_my, (unsigned int)(t + 2));
            }
            // out stores AFTER the flag (cached, off the release path)
#pragma unroll
            for (int r = 0; r < 4; ++r) {
                int b = mg * 16 + quad * 4 + r;
                out[(size_t)b * (1024 * 512) + (size_t)t * 512 + jg] = h_reg[r];
            }
            if (t < 1023) {
                // prefetch next step's x projections; complete during next poll
                const unsigned short* Xt = X + (size_t)(t + 1) * (64 * 1536);
#pragma unroll
                for (int r = 0; r < 4; ++r) {
                    int b = mg * 16 + quad * 4 + r;
#pragma unroll
                    for (int g = 0; g < 3; ++g)
                        xv[g][r] = bf2f(Xt[b * 1536 + g * 512 + jg]);
                }
            } else {
#pragma unroll
                for (int r = 0; r < 4; ++r) {
                    int b = mg * 16 + quad * 4 + r;
                    out[(size_t)(64 * 1024 * 512) + b * 512 + jg] = h_reg[r];
                }
            }
        }
    }
}

// ---------------------------------------------------------------- host
extern "C" void kernel_launch(void* const* d_in, const int* in_sizes, int n_in,
                              void* d_out, int out_size, void* d_ws, size_t ws_size,
                              hipStream_t stream) {
    const float* inputs = (const float*)d_in[0];
    const float* h0     = (const float*)d_in[1];
    const float* w_ir   = (const float*)d_in[2];
    const float* w_iz   = (const float*)d_in[3];
    const float* w_in   = (const float*)d_in[4];
    const float* b_ir   = (const float*)d_in[5];
    const float* b_iz   = (const float*)d_in[6];
    const float* b_in   = (const float*)d_in[7];
    const float* w_hr   = (const float*)d_in[8];
    const float* w_hz   = (const float*)d_in[9];
    const float* w_hn   = (const float*)d_in[10];
    const float* b_hr   = (const float*)d_in[11];
    const float* b_hz   = (const float*)d_in[12];
    const float* b_hn   = (const float*)d_in[13];
    float* out = (float*)d_out;

    // ws layout (16B aligned)
    char* wsb = (char*)d_ws;
    unsigned short*     X     = (unsigned short*)(wsb);              // 201326592 B
    unsigned short*     Abf   = (unsigned short*)(wsb + 201326592);  //  33554432 B
    unsigned short*     Wx    = (unsigned short*)(wsb + 234881024);  //    786432 B
    unsigned short*     Wh    = (unsigned short*)(wsb + 235667456);  //   1572864 B
    float*              biasx = (float*)        (wsb + 237240320);   //      6144 B
    unsigned long long* Hp64  = (unsigned long long*)(wsb + 237246464); // 131072 B
    unsigned int*       flags = (unsigned int*) (wsb + 237377536);   //     16384 B (end 237393920)

    pack_inputs<<<16384, 256, 0, stream>>>(inputs, Abf);
    pack_weights<<<3072, 256, 0, stream>>>(w_ir, w_iz, w_in, b_ir, b_iz, b_in,
                                           w_hr, w_hz, w_hn, b_hr, b_hz, Wx, Wh, biasx, flags);
    xproj_gemm<<<dim3(1024, 24), 256, 0, stream>>>(Abf, Wx, biasx, X);
    gru_scan<<<32, 512, 0, stream>>>(X, Wh, h0, b_hn, Hp64, flags, out);
}